// Round 13
// baseline (400.596 us; speedup 1.0000x reference)
//
#include <hip/hip_runtime.h>

// ---------------------------------------------------------------------------
// GAT 3-layer forward on MI355X. R13: MLP boost for edge-wise kernels.
//   deg_pos and scatter2 process 4 edges/thread (grid-stride, fully
//   co-resident) -> 4 independent memory chains in flight per thread.
// Everything else unchanged from R12.
// ---------------------------------------------------------------------------

#define NEG_SLOPE 0.2f
#define SM_EPS 1e-16f
#define SCAN_CHUNK 2048

typedef __bf16 bf16x8 __attribute__((ext_vector_type(8)));
typedef float f32x4 __attribute__((ext_vector_type(4)));
typedef unsigned int u32x4 __attribute__((ext_vector_type(4)));

__device__ __forceinline__ float bf2f(unsigned short u) {
  union { unsigned int i; float f; } v; v.i = ((unsigned int)u) << 16; return v.f;
}
__device__ __forceinline__ unsigned short f2bf(float f) {
  union { float f; unsigned int i; } v; v.f = f;
  unsigned int lsb = (v.i >> 16) & 1u;
  v.i += 0x7fffu + lsb;  // RNE
  return (unsigned short)(v.i >> 16);
}
__device__ __forceinline__ void bf2x(unsigned int u, float& f0, float& f1) {
  union { unsigned int i; float f; } a, b;
  a.i = u << 16; b.i = u & 0xffff0000u;
  f0 = a.f; f1 = b.f;
}

// --- edge dtype detection: int64 arrays read as int32 have zero odd words ---
__global__ void detect_i64_kernel(const int* __restrict__ ei, int* __restrict__ flag) {
  if (blockIdx.x == 0 && threadIdx.x == 0) {
    int orv = 0;
    for (int k = 0; k < 64; ++k) orv |= ei[2 * k + 1];
    *flag = (orv == 0) ? 1 : 0;
  }
}

__device__ __forceinline__ int load_idx(const int* __restrict__ ei, int logical, int is64) {
  return is64 ? ei[2 * logical] : ei[logical];
}

// --- prep_mega: deg_pos(4 edges/thr) | k1_asv1 | weight transpose | A2 prep -
__global__ __launch_bounds__(256) void prep_mega(
    const int* __restrict__ ei, int E, const int* __restrict__ flag,
    int* __restrict__ cnt, int* __restrict__ pos,
    const float* __restrict__ x, const float* __restrict__ W1,
    const float* __restrict__ as1, const float* __restrict__ ad1,
    float* __restrict__ asv, float* __restrict__ adv, int N,
    const float* __restrict__ W2, const float* __restrict__ W3,
    unsigned short* __restrict__ w2t, unsigned short* __restrict__ w3t,
    const float* __restrict__ as2, const float* __restrict__ ad2,
    float* __restrict__ A2s, float* __restrict__ A2d,
    int nbDeg, int nbK1, int nbWt) {
  int bid = blockIdx.x;
  int t = threadIdx.x;
  if (bid < nbDeg) {
    // pass 1 of CSR: count + record within-segment position, 4 edges/thread
    int is64 = *flag;
    int base = bid * 1024;
    int i0 = base + t, i1 = base + 256 + t, i2 = base + 512 + t, i3 = base + 768 + t;
    int d0 = (i0 < E) ? load_idx(ei, E + i0, is64) : -1;
    int d1 = (i1 < E) ? load_idx(ei, E + i1, is64) : -1;
    int d2 = (i2 < E) ? load_idx(ei, E + i2, is64) : -1;
    int d3 = (i3 < E) ? load_idx(ei, E + i3, is64) : -1;
    int p0 = (d0 >= 0) ? atomicAdd(&cnt[d0], 1) : 0;
    int p1 = (d1 >= 0) ? atomicAdd(&cnt[d1], 1) : 0;
    int p2 = (d2 >= 0) ? atomicAdd(&cnt[d2], 1) : 0;
    int p3 = (d3 >= 0) ? atomicAdd(&cnt[d3], 1) : 0;
    if (d0 >= 0) pos[i0] = p0;
    if (d1 >= 0) pos[i1] = p1;
    if (d2 >= 0) pos[i2] = p2;
    if (d3 >= 0) pos[i3] = p3;
  } else if (bid < nbDeg + nbK1) {
    // k1: asv1/adv1 via block-local A1 = W1^T a1 (3x4, computed in LDS)
    __shared__ float A1[24];
    if (t < 24) {
      int e = t % 12;
      int k = e >> 2, h = e & 3;
      const float* av = (t < 12) ? as1 : ad1;
      const float* wr = W1 + k * 256 + h * 64;
      const float* a = av + h * 64;
      float v = 0.f;
      for (int c = 0; c < 64; ++c) v += wr[c] * a[c];
      A1[t] = v;
    }
    __syncthreads();
    int n = (bid - nbDeg) * 256 + t;
    if (n < N) {
      float x0 = x[n * 3 + 0], x1 = x[n * 3 + 1], x2 = x[n * 3 + 2];
      f32x4 s, d;
#pragma unroll
      for (int h = 0; h < 4; ++h) {
        s[h] = x0 * A1[h] + x1 * A1[4 + h] + x2 * A1[8 + h];
        d[h] = x0 * A1[12 + h] + x1 * A1[16 + h] + x2 * A1[20 + h];
      }
      *(f32x4*)(asv + (size_t)n * 4) = s;
      *(f32x4*)(adv + (size_t)n * 4) = d;
    }
  } else if (bid < nbDeg + nbK1 + nbWt) {
    // weight transpose + bf16 cast
    int idx = (bid - nbDeg - nbK1) * 256 + t;
    if (idx < 256 * 256) {
      int k = idx >> 8, n = idx & 255;
      w2t[(size_t)n * 256 + k] = f2bf(W2[idx]);
    } else {
      int j = idx - 256 * 256;
      if (j < 256 * 32) {
        int k = j >> 5, n = j & 31;
        w3t[(size_t)n * 256 + k] = f2bf(W3[j]);
      }
    }
  } else {
    // A2s/A2d = W2 a2 (256x4 each)
    int c = t;
#pragma unroll
    for (int h = 0; h < 4; ++h) {
      float vs = 0.f, vd = 0.f;
      const float* wrow = W2 + (size_t)c * 256 + h * 64;
      const float* s2 = as2 + h * 64;
      const float* d2 = ad2 + h * 64;
      for (int cc = 0; cc < 64; ++cc) {
        float w = wrow[cc];
        vs += w * s2[cc];
        vd += w * d2[cc];
      }
      A2s[c * 4 + h] = vs;
      A2d[c * 4 + h] = vd;
    }
  }
}

__global__ __launch_bounds__(256) void scan_phaseA(const int* __restrict__ deg,
                                                   int* __restrict__ bsum, int N) {
  int t = threadIdx.x;
  int base = blockIdx.x * SCAN_CHUNK + t * 8;
  int s = 0;
#pragma unroll
  for (int i = 0; i < 8; ++i) {
    int idx = base + i;
    if (idx < N) s += deg[idx] + 1;
  }
  __shared__ int red[256];
  red[t] = s;
  __syncthreads();
  for (int d = 128; d > 0; d >>= 1) {
    if (t < d) red[t] += red[t + d];
    __syncthreads();
  }
  if (t == 0) bsum[blockIdx.x] = red[0];
}

__global__ __launch_bounds__(256) void scan_phaseC(const int* __restrict__ deg,
                                                   const int* __restrict__ bsum,
                                                   int* __restrict__ rowptr, int N) {
  int t = threadIdx.x;
  __shared__ int blkoff;
  if (t == 0) {
    int o = 0;
    for (int i = 0; i < (int)blockIdx.x; ++i) o += bsum[i];
    blkoff = o;
  }
  int base = blockIdx.x * SCAN_CHUNK + t * 8;
  int v[8];
  int s = 0;
#pragma unroll
  for (int i = 0; i < 8; ++i) {
    int idx = base + i;
    v[i] = (idx < N) ? deg[idx] + 1 : 0;
    s += v[i];
  }
  __shared__ int sh[256];
  sh[t] = s;
  __syncthreads();
  for (int d = 1; d < 256; d <<= 1) {
    int u = (t >= d) ? sh[t - d] : 0;
    __syncthreads();
    sh[t] += u;
    __syncthreads();
  }
  int run = blkoff + sh[t] - s;
#pragma unroll
  for (int i = 0; i < 8; ++i) {
    int idx = base + i;
    if (idx < N) rowptr[idx] = run;
    run += v[i];
  }
  if (base < N && base + 8 >= N) rowptr[N] = run;
}

// pass 2 of CSR: pure permutation write, no atomics, 4 edges/thread
__global__ __launch_bounds__(256) void scatter2_kernel(
    const int* __restrict__ ei, int E, int N, const int* __restrict__ flag,
    const int* __restrict__ rowptr, const int* __restrict__ pos,
    int* __restrict__ colA) {
  int is64 = *flag;
  int ET = E + N;
  int base = blockIdx.x * 1024;
#pragma unroll
  for (int k = 0; k < 4; ++k) {
    int i = base + k * 256 + (int)threadIdx.x;
    if (i < E) {
      int s = load_idx(ei, i, is64);
      int d = load_idx(ei, E + i, is64);
      __builtin_nontemporal_store(s, &colA[rowptr[d] + pos[i]]);
    } else if (i < ET) {
      int n = i - E;
      __builtin_nontemporal_store(n, &colA[rowptr[n + 1] - 1]);  // self loop: last slot
    }
  }
}

// --- k2_fused: layer-1 agg of raw x + W1 expansion + asv2 epilogue ---------
__global__ __launch_bounds__(256) void k2_fused(
    const float* __restrict__ x, const float* __restrict__ asv,
    const float* __restrict__ adv, const int* __restrict__ rowptr,
    const int* __restrict__ colA, const float* __restrict__ W1,
    const float* __restrict__ b1, const float* __restrict__ A2s,
    const float* __restrict__ A2d, unsigned short* __restrict__ h,
    float* __restrict__ asv2, float* __restrict__ adv2, int N) {
  int wv = threadIdx.x >> 6;
  int d = blockIdx.x * 4 + wv;
  if (d >= N) return;
  int lane = threadIdx.x & 63;
  int h4 = lane >> 4, el = lane & 15;
  int r0 = rowptr[d], r1 = rowptr[d + 1];
  int len = r1 - r0;
  float ad = adv[(size_t)d * 4 + h4];
  float m = -1e30f, s = 0.f;
  float ax = 0.f, ay = 0.f, az = 0.f;
  for (int base = 0; base < len; base += 16) {
    int rem = len - base; if (rem > 16) rem = 16;
    int sc = 0;
    float alpha = -1e30f;
    if (el < rem) {
      sc = colA[r0 + base + el];
      float a = asv[(size_t)sc * 4 + h4] + ad;
      alpha = (a > 0.f) ? a : NEG_SLOPE * a;
    }
    float mx = alpha;
#pragma unroll
    for (int off = 1; off < 16; off <<= 1) mx = fmaxf(mx, __shfl_xor(mx, off));
    float mn = fmaxf(m, mx);
    float scale = __expf(m - mn);
    float w = (el < rem) ? __expf(alpha - mn) : 0.f;
    float cs = w;
#pragma unroll
    for (int off = 1; off < 16; off <<= 1) cs += __shfl_xor(cs, off);
    s = s * scale + cs;
    m = mn;
    ax *= scale; ay *= scale; az *= scale;
    if (el < rem) {
      ax += w * x[(size_t)sc * 3 + 0];
      ay += w * x[(size_t)sc * 3 + 1];
      az += w * x[(size_t)sc * 3 + 2];
    }
  }
#pragma unroll
  for (int off = 1; off < 16; off <<= 1) {
    ax += __shfl_xor(ax, off);
    ay += __shfl_xor(ay, off);
    az += __shfl_xor(az, off);
  }
  float inv = 1.f / (s + SM_EPS);
  ax *= inv; ay *= inv; az *= inv;
  float vs[4] = {}, vd[4] = {};
  unsigned short o[4];
#pragma unroll
  for (int j = 0; j < 4; ++j) {
    int c = lane * 4 + j;
    float val = ax * W1[c] + ay * W1[256 + c] + az * W1[512 + c] + b1[c];
    val = fmaxf(val, 0.f);
    o[j] = f2bf(val);
#pragma unroll
    for (int h2 = 0; h2 < 4; ++h2) {
      vs[h2] += val * A2s[c * 4 + h2];
      vd[h2] += val * A2d[c * 4 + h2];
    }
  }
  *(uint2*)(h + (size_t)d * 256 + lane * 4) = *(uint2*)o;
#pragma unroll
  for (int off = 1; off < 64; off <<= 1) {
#pragma unroll
    for (int h2 = 0; h2 < 4; ++h2) {
      vs[h2] += __shfl_xor(vs[h2], off);
      vd[h2] += __shfl_xor(vd[h2], off);
    }
  }
  if (lane == 0) {
    f32x4 sv, dv;
#pragma unroll
    for (int h2 = 0; h2 < 4; ++h2) { sv[h2] = vs[h2]; dv[h2] = vd[h2]; }
    *(f32x4*)(asv2 + (size_t)d * 4) = sv;
    *(f32x4*)(adv2 + (size_t)d * 4) = dv;
  }
}

// --- layer-2 GEMM: [M,256]@[256,256], BM=128 x BN=256, 512 threads ---------
__global__ __launch_bounds__(512) void gemm_mfma_w256(
    const unsigned short* __restrict__ A, const unsigned short* __restrict__ Bt,
    unsigned short* __restrict__ C, int M, int K) {
  constexpr int BM = 128, BK = 64;
  __shared__ unsigned short As[BM][BK + 8];
  __shared__ unsigned short Bs[256][BK + 8];
  const int bm = blockIdx.x * BM;
  const int tid = threadIdx.x, wid = tid >> 6, lane = tid & 63;
  const int wr = wid >> 2, wc = wid & 3;
  const int lrow = lane & 15, lkh = lane >> 4;
  const int srow = tid >> 3, scol = (tid & 7) * 8;
  f32x4 acc[4][4] = {};
  for (int k0 = 0; k0 < K; k0 += BK) {
#pragma unroll
    for (int r0 = 0; r0 < BM; r0 += 64) {
      int r = r0 + srow, gr = bm + r;
      uint4 v = make_uint4(0u, 0u, 0u, 0u);
      if (gr < M) v = *(const uint4*)(A + (size_t)gr * K + k0 + scol);
      *(uint4*)(&As[r][scol]) = v;
    }
#pragma unroll
    for (int r0 = 0; r0 < 256; r0 += 64) {
      int r = r0 + srow;
      uint4 v = *(const uint4*)(Bt + (size_t)r * K + k0 + scol);
      *(uint4*)(&Bs[r][scol]) = v;
    }
    __syncthreads();
#pragma unroll
    for (int kk = 0; kk < 2; ++kk) {
      bf16x8 a[4], b[4];
#pragma unroll
      for (int m = 0; m < 4; ++m)
        a[m] = *(const bf16x8*)(&As[wr * 64 + m * 16 + lrow][kk * 32 + lkh * 8]);
#pragma unroll
      for (int n = 0; n < 4; ++n)
        b[n] = *(const bf16x8*)(&Bs[wc * 64 + n * 16 + lrow][kk * 32 + lkh * 8]);
#pragma unroll
      for (int m = 0; m < 4; ++m)
#pragma unroll
        for (int n = 0; n < 4; ++n)
          acc[m][n] = __builtin_amdgcn_mfma_f32_16x16x32_bf16(a[m], b[n], acc[m][n], 0, 0, 0);
    }
    __syncthreads();
  }
#pragma unroll
  for (int m = 0; m < 4; ++m) {
#pragma unroll
    for (int q = 0; q < 4; ++q) {
      int grow = bm + wr * 64 + m * 16 + lkh * 4 + q;
      if (grow < M) {
#pragma unroll
        for (int n = 0; n < 4; ++n)
          C[(size_t)grow * 256 + wc * 64 + n * 16 + lrow] = f2bf(acc[m][n][q]);
      }
    }
  }
}

// --- layer-3 GEMM: BM=128 x BN=32 (full width), fused attn (H=1) -----------
template <int WR, int WC, int ATT_H>
__global__ __launch_bounds__(64 * WR * WC) void gemm_mfma(
    const unsigned short* __restrict__ A, const unsigned short* __restrict__ Bt,
    unsigned short* __restrict__ C, const float* __restrict__ a_src,
    const float* __restrict__ a_dst, float* __restrict__ asv, float* __restrict__ adv,
    int M, int N, int K) {
  constexpr int BM = 32 * WR, BN = 32 * WC, BK = 64;
  constexpr int T = 64 * WR * WC;
  constexpr int RPP = T / 8;
  __shared__ unsigned short As[BM][BK + 8];
  __shared__ unsigned short Bs[BN][BK + 8];
  const int bm = blockIdx.y * BM, bn = blockIdx.x * BN;
  const int tid = threadIdx.x, wid = tid >> 6, lane = tid & 63;
  const int wr = wid / WC, wc = wid % WC;
  const int lrow = lane & 15, lkh = lane >> 4;
  const int srow = tid >> 3, scol = (tid & 7) * 8;
  f32x4 acc[2][2] = {};
  for (int k0 = 0; k0 < K; k0 += BK) {
#pragma unroll
    for (int r0 = 0; r0 < BM; r0 += RPP) {
      int r = r0 + srow, gr = bm + r;
      uint4 v = make_uint4(0u, 0u, 0u, 0u);
      if (gr < M) v = *(const uint4*)(A + (size_t)gr * K + k0 + scol);
      *(uint4*)(&As[r][scol]) = v;
    }
#pragma unroll
    for (int r0 = 0; r0 < BN; r0 += RPP) {
      int r = r0 + srow;
      if (r < BN) {
        int gn = bn + r;
        uint4 v = *(const uint4*)(Bt + (size_t)gn * K + k0 + scol);
        *(uint4*)(&Bs[r][scol]) = v;
      }
    }
    __syncthreads();
#pragma unroll
    for (int kk = 0; kk < 2; ++kk) {
      bf16x8 a0 = *(const bf16x8*)(&As[wr * 32 + lrow][kk * 32 + lkh * 8]);
      bf16x8 a1 = *(const bf16x8*)(&As[wr * 32 + 16 + lrow][kk * 32 + lkh * 8]);
      bf16x8 b0 = *(const bf16x8*)(&Bs[wc * 32 + lrow][kk * 32 + lkh * 8]);
      bf16x8 b1 = *(const bf16x8*)(&Bs[wc * 32 + 16 + lrow][kk * 32 + lkh * 8]);
      acc[0][0] = __builtin_amdgcn_mfma_f32_16x16x32_bf16(a0, b0, acc[0][0], 0, 0, 0);
      acc[0][1] = __builtin_amdgcn_mfma_f32_16x16x32_bf16(a0, b1, acc[0][1], 0, 0, 0);
      acc[1][0] = __builtin_amdgcn_mfma_f32_16x16x32_bf16(a1, b0, acc[1][0], 0, 0, 0);
      acc[1][1] = __builtin_amdgcn_mfma_f32_16x16x32_bf16(a1, b1, acc[1][1], 0, 0, 0);
    }
    __syncthreads();
  }
#pragma unroll
  for (int m = 0; m < 2; ++m) {
#pragma unroll
    for (int q = 0; q < 4; ++q) {
      int grow = bm + wr * 32 + m * 16 + lkh * 4 + q;
      if (grow < M) {
#pragma unroll
        for (int n = 0; n < 2; ++n) {
          int gcol = bn + wc * 32 + n * 16 + lrow;
          C[(size_t)grow * N + gcol] = f2bf(acc[m][n][q]);
        }
      }
    }
  }
  const int hh = (ATT_H == 1) ? 0 : (int)blockIdx.x;
  float asl[2], adl[2];
#pragma unroll
  for (int n = 0; n < 2; ++n) {
    int c = wc * 32 + n * 16 + lrow;
    asl[n] = a_src[hh * BN + c];
    adl[n] = a_dst[hh * BN + c];
  }
#pragma unroll
  for (int m = 0; m < 2; ++m) {
#pragma unroll
    for (int q = 0; q < 4; ++q) {
      float ps = acc[m][0][q] * asl[0] + acc[m][1][q] * asl[1];
      float pd = acc[m][0][q] * adl[0] + acc[m][1][q] * adl[1];
#pragma unroll
      for (int off = 1; off < 16; off <<= 1) {
        ps += __shfl_xor(ps, off);
        pd += __shfl_xor(pd, off);
      }
      int grow = bm + wr * 32 + m * 16 + lkh * 4 + q;
      if (lrow == 0 && grow < M) {
        asv[(size_t)grow * ATT_H + hh] = ps;
        adv[(size_t)grow * ATT_H + hh] = pd;
      }
    }
  }
}

// --- single-pass fused softmax+gather, H=4 C=64: wave per dst --------------
template <bool RELU>
__global__ __launch_bounds__(256) void gat_fused256(
    const unsigned short* __restrict__ hbuf, const float* __restrict__ asv,
    const float* __restrict__ adv, const int* __restrict__ rowptr,
    const int* __restrict__ colA, const float* __restrict__ bias,
    unsigned short* __restrict__ outb, int N) {
  int wv = threadIdx.x >> 6;
  int d = blockIdx.x * 4 + wv;
  if (d >= N) return;
  int lane = threadIdx.x & 63;
  int h4 = lane >> 4, el = lane & 15;       // stats role
  int g = lane >> 5, c32 = lane & 31;       // gather role
  int hh = c32 >> 3;
  int r0 = rowptr[d], r1 = rowptr[d + 1];
  int len = r1 - r0;
  float ad = adv[(size_t)d * 4 + h4];
  float m = -1e30f, s = 0.f;
  float acc[8] = {};
  const int hsrc = hh * 16;
  for (int base = 0; base < len; base += 16) {
    int rem = len - base; if (rem > 16) rem = 16;
    int sc = 0;
    float alpha = -1e30f;
    if (el < rem) {
      sc = colA[r0 + base + el];
      float a = asv[(size_t)sc * 4 + h4] + ad;
      alpha = (a > 0.f) ? a : NEG_SLOPE * a;
    }
    float mx = alpha;
#pragma unroll
    for (int off = 1; off < 16; off <<= 1) mx = fmaxf(mx, __shfl_xor(mx, off));
    float mn = fmaxf(m, mx);
    float scale = __expf(m - mn);
    float w = (el < rem) ? __expf(alpha - mn) : 0.f;
    float cs = w;
#pragma unroll
    for (int off = 1; off < 16; off <<= 1) cs += __shfl_xor(cs, off);
    s = s * scale + cs;
    m = mn;
    float scale_h = __shfl(scale, hsrc);
#pragma unroll
    for (int j = 0; j < 8; ++j) acc[j] *= scale_h;
    int e2 = 0;
    for (; e2 + 4 <= rem; e2 += 4) {
      int ea = e2 + g, eb = e2 + 2 + g;
      float wa = __shfl(w, hsrc + ea);
      int sa = __shfl(sc, hsrc + ea);
      float wb = __shfl(w, hsrc + eb);
      int sb = __shfl(sc, hsrc + eb);
      uint4 hva = *(const uint4*)(hbuf + (size_t)sa * 256 + c32 * 8);
      uint4 hvb = *(const uint4*)(hbuf + (size_t)sb * 256 + c32 * 8);
      float f0, f1;
      bf2x(hva.x, f0, f1); acc[0] += wa * f0; acc[1] += wa * f1;
      bf2x(hva.y, f0, f1); acc[2] += wa * f0; acc[3] += wa * f1;
      bf2x(hva.z, f0, f1); acc[4] += wa * f0; acc[5] += wa * f1;
      bf2x(hva.w, f0, f1); acc[6] += wa * f0; acc[7] += wa * f1;
      bf2x(hvb.x, f0, f1); acc[0] += wb * f0; acc[1] += wb * f1;
      bf2x(hvb.y, f0, f1); acc[2] += wb * f0; acc[3] += wb * f1;
      bf2x(hvb.z, f0, f1); acc[4] += wb * f0; acc[5] += wb * f1;
      bf2x(hvb.w, f0, f1); acc[6] += wb * f0; acc[7] += wb * f1;
    }
    for (; e2 < rem; e2 += 2) {
      int e = e2 + g;
      float w_e = __shfl(w, hsrc + (e & 15));
      int sc_e = __shfl(sc, hsrc + (e & 15));
      uint4 hv = *(const uint4*)(hbuf + (size_t)sc_e * 256 + c32 * 8);
      float f0, f1;
      bf2x(hv.x, f0, f1); acc[0] += w_e * f0; acc[1] += w_e * f1;
      bf2x(hv.y, f0, f1); acc[2] += w_e * f0; acc[3] += w_e * f1;
      bf2x(hv.z, f0, f1); acc[4] += w_e * f0; acc[5] += w_e * f1;
      bf2x(hv.w, f0, f1); acc[6] += w_e * f0; acc[7] += w_e * f1;
    }
  }
#pragma unroll
  for (int j = 0; j < 8; ++j) acc[j] += __shfl_xor(acc[j], 32);
  float inv = 1.f / (__shfl(s, hsrc) + SM_EPS);
  if (g == 0) {
    unsigned short o[8];
#pragma unroll
    for (int j = 0; j < 8; ++j) {
      float v = acc[j] * inv + bias[c32 * 8 + j];
      if (RELU) v = fmaxf(v, 0.f);
      o[j] = f2bf(v);
    }
    __builtin_nontemporal_store(*(u32x4*)o, (u32x4*)(outb + (size_t)d * 256 + c32 * 8));
  }
}

// --- single-pass fused softmax+gather, H=1 C=32 (layer 3), fp32 out --------
__global__ __launch_bounds__(256) void gat_fused32(
    const unsigned short* __restrict__ hbuf, const float* __restrict__ asv,
    const float* __restrict__ adv, const int* __restrict__ rowptr,
    const int* __restrict__ colA, const float* __restrict__ bias,
    float* __restrict__ out, int N) {
  int wv = threadIdx.x >> 6;
  int d = blockIdx.x * 4 + wv;
  if (d >= N) return;
  int lane = threadIdx.x & 63;
  int slot = lane >> 3, ci = lane & 7;
  int r0 = rowptr[d], r1 = rowptr[d + 1];
  int len = r1 - r0;
  float ad = adv[d];
  float m = -1e30f, s = 0.f;
  float a0 = 0.f, a1 = 0.f, a2 = 0.f, a3 = 0.f;
  for (int base = 0; base < len; base += 64) {
    int rem = len - base; if (rem > 64) rem = 64;
    int sc = 0;
    float alpha = -1e30f;
    if (lane < rem) {
      sc = colA[r0 + base + lane];
      float a = asv[sc] + ad;
      alpha = (a > 0.f) ? a : NEG_SLOPE * a;
    }
    float mx = alpha;
#pragma unroll
    for (int off = 1; off < 64; off <<= 1) mx = fmaxf(mx, __shfl_xor(mx, off));
    float mn = fmaxf(m, mx);
    float scale = __expf(m - mn);
    float w = (lane < rem) ? __expf(alpha - mn) : 0.f;
    float cs = w;
#pragma unroll
    for (int off = 1; off < 64; off <<= 1) cs += __shfl_xor(cs, off);
    s = s * scale + cs;
    m = mn;
    a0 *= scale; a1 *= scale; a2 *= scale; a3 *= scale;
    for (int e2 = 0; e2 < rem; e2 += 8) {
      int e = e2 + slot;
      float w_e = __shfl(w, e);
      int sc_e = __shfl(sc, e);
      uint2 hv = *(const uint2*)(hbuf + (size_t)sc_e * 32 + ci * 4);
      float f0, f1;
      bf2x(hv.x, f0, f1); a0 += w_e * f0; a1 += w_e * f1;
      bf2x(hv.y, f0, f1); a2 += w_e * f0; a3 += w_e * f1;
    }
  }
#pragma unroll
  for (int off = 8; off < 64; off <<= 1) {
    a0 += __shfl_xor(a0, off);
    a1 += __shfl_xor(a1, off);
    a2 += __shfl_xor(a2, off);
    a3 += __shfl_xor(a3, off);
  }
  if (slot == 0) {
    float inv = 1.f / (s + SM_EPS);
    f32x4 o;
    o.x = a0 * inv + bias[ci * 4 + 0];
    o.y = a1 * inv + bias[ci * 4 + 1];
    o.z = a2 * inv + bias[ci * 4 + 2];
    o.w = a3 * inv + bias[ci * 4 + 3];
    __builtin_nontemporal_store(o, (f32x4*)(out + (size_t)d * 32 + ci * 4));
  }
}

// ---------------------------------------------------------------------------
extern "C" void kernel_launch(void* const* d_in, const int* in_sizes, int n_in,
                              void* d_out, int out_size, void* d_ws, size_t ws_size,
                              hipStream_t stream) {
  const float* x   = (const float*)d_in[0];
  const int*   ei  = (const int*)d_in[1];
  const float* W1  = (const float*)d_in[2];
  const float* as1 = (const float*)d_in[3];
  const float* ad1 = (const float*)d_in[4];
  const float* b1  = (const float*)d_in[5];
  const float* W2  = (const float*)d_in[6];
  const float* as2 = (const float*)d_in[7];
  const float* ad2 = (const float*)d_in[8];
  const float* b2  = (const float*)d_in[9];
  const float* W3  = (const float*)d_in[10];
  const float* as3 = (const float*)d_in[11];
  const float* ad3 = (const float*)d_in[12];
  const float* b3  = (const float*)d_in[13];
  float* out = (float*)d_out;

  const int N = in_sizes[0] / 3;
  const int E = in_sizes[1] / 2;
  const int ET = E + N;  // with self loops

  char* ws = (char*)d_ws;
  size_t off = 0;
  auto alloc = [&](size_t bytes) -> void* {
    void* p = ws + off;
    off = (off + bytes + 255) & ~(size_t)255;
    return p;
  };
  unsigned short* bufA = (unsigned short*)alloc((size_t)N * 256 * 2);
  unsigned short* bufB = (unsigned short*)alloc((size_t)N * 256 * 2);
  unsigned short* w2t  = (unsigned short*)alloc((size_t)256 * 256 * 2);
  unsigned short* w3t  = (unsigned short*)alloc((size_t)32 * 256 * 2);
  float* asbuf  = (float*)alloc((size_t)N * 4 * 4);
  float* adbuf  = (float*)alloc((size_t)N * 4 * 4);
  float* asbuf2 = (float*)alloc((size_t)N * 4 * 4);
  float* adbuf2 = (float*)alloc((size_t)N * 4 * 4);
  int*   rowptr = (int*)alloc((size_t)(N + 1) * 4);
  int*   cnt    = (int*)alloc((size_t)N * 4);
  int*   posb   = (int*)alloc((size_t)E * 4);
  int*   colA   = (int*)alloc((size_t)ET * 4);
  int*   bsum   = (int*)alloc(1024);
  int*   dflag  = (int*)alloc(256);
  float* A2s    = (float*)alloc(1024 * 4);
  float* A2d    = (float*)alloc(1024 * 4);
  (void)ws_size;

  const int nScanB = (N + SCAN_CHUNK - 1) / SCAN_CHUNK;
  const int nbDeg = (E + 1023) / 1024;
  const int nbK1  = (N + 255) / 256;
  const int nbWt  = (256 * 256 + 256 * 32 + 255) / 256;

  // --- CSR build + weight prep (fused) ---
  detect_i64_kernel<<<1, 64, 0, stream>>>(ei, dflag);
  hipMemsetAsync(cnt, 0, (size_t)N * 4, stream);
  prep_mega<<<nbDeg + nbK1 + nbWt + 1, 256, 0, stream>>>(
      ei, E, dflag, cnt, posb, x, W1, as1, ad1, asbuf, adbuf, N,
      W2, W3, w2t, w3t, as2, ad2, A2s, A2d, nbDeg, nbK1, nbWt);
  scan_phaseA<<<nScanB, 256, 0, stream>>>(cnt, bsum, N);
  scan_phaseC<<<nScanB, 256, 0, stream>>>(cnt, bsum, rowptr, N);
  scatter2_kernel<<<(ET + 1023) / 1024, 256, 0, stream>>>(ei, E, N, dflag, rowptr, posb, colA);

  const int nb4 = (N + 3) / 4;

  // --- layer 1: fused agg(raw x) + W1 expand + asv2 epilogue -> bufB ---
  k2_fused<<<nb4, 256, 0, stream>>>(x, asbuf, adbuf, rowptr, colA, W1, b1,
                                    A2s, A2d, bufB, asbuf2, adbuf2, N);

  // --- layer 2: h2 = h1 @ W2 (MFMA) -> bufA ; fused agg -> bufB ---
  gemm_mfma_w256<<<(N + 127) / 128, 512, 0, stream>>>(bufB, w2t, bufA, N, 256);
  gat_fused256<true><<<nb4, 256, 0, stream>>>(bufA, asbuf2, adbuf2, rowptr, colA, b2, bufB, N);

  // --- layer 3: MFMA GEMM+attn -> bufA[0:N*32] ; fused agg -> out ---
  {
    dim3 grid(1, (N + 127) / 128);
    gemm_mfma<4, 1, 1><<<grid, 256, 0, stream>>>(bufB, w3t, bufA, as3, ad3, asbuf, adbuf,
                                                 N, 32, 256);
  }
  gat_fused32<<<nb4, 256, 0, stream>>>(bufA, asbuf, adbuf, rowptr, colA, b3, out, N);
}

// Round 14
// 399.818 us; speedup vs baseline: 1.0019x; 1.0019x over previous
//
#include <hip/hip_runtime.h>

// ---------------------------------------------------------------------------
// GAT 3-layer forward on MI355X. R14: random-line reduction for k2.
//   xa[n] = {x0,x1,x2,pad, as1[0..3]} packed 32B -> k2_fused does ONE random
//   line per edge (was 2 + a payload re-read). zero_detect folds memset+detect.
// ---------------------------------------------------------------------------

#define NEG_SLOPE 0.2f
#define SM_EPS 1e-16f
#define SCAN_CHUNK 2048

typedef __bf16 bf16x8 __attribute__((ext_vector_type(8)));
typedef float f32x4 __attribute__((ext_vector_type(4)));
typedef unsigned int u32x4 __attribute__((ext_vector_type(4)));

__device__ __forceinline__ float bf2f(unsigned short u) {
  union { unsigned int i; float f; } v; v.i = ((unsigned int)u) << 16; return v.f;
}
__device__ __forceinline__ unsigned short f2bf(float f) {
  union { float f; unsigned int i; } v; v.f = f;
  unsigned int lsb = (v.i >> 16) & 1u;
  v.i += 0x7fffu + lsb;  // RNE
  return (unsigned short)(v.i >> 16);
}
__device__ __forceinline__ void bf2x(unsigned int u, float& f0, float& f1) {
  union { unsigned int i; float f; } a, b;
  a.i = u << 16; b.i = u & 0xffff0000u;
  f0 = a.f; f1 = b.f;
}

__device__ __forceinline__ int load_idx(const int* __restrict__ ei, int logical, int is64) {
  return is64 ? ei[2 * logical] : ei[logical];
}

// --- zero cnt + edge dtype detection in one launch --------------------------
__global__ __launch_bounds__(256) void zero_detect(const int* __restrict__ ei,
                                                   int* __restrict__ flag,
                                                   int* __restrict__ cnt, int N) {
  int i = blockIdx.x * 256 + threadIdx.x;
  if (i < N) cnt[i] = 0;
  if (blockIdx.x == 0 && threadIdx.x == 0) {
    int orv = 0;
    for (int k = 0; k < 64; ++k) orv |= ei[2 * k + 1];
    *flag = (orv == 0) ? 1 : 0;
  }
}

// --- prep_mega: deg_pos(4 edges/thr) | k1(xa,adv) | weight transpose | A2 ---
__global__ __launch_bounds__(256) void prep_mega(
    const int* __restrict__ ei, int E, const int* __restrict__ flag,
    int* __restrict__ cnt, int* __restrict__ pos,
    const float* __restrict__ x, const float* __restrict__ W1,
    const float* __restrict__ as1, const float* __restrict__ ad1,
    float* __restrict__ xa, float* __restrict__ adv, int N,
    const float* __restrict__ W2, const float* __restrict__ W3,
    unsigned short* __restrict__ w2t, unsigned short* __restrict__ w3t,
    const float* __restrict__ as2, const float* __restrict__ ad2,
    float* __restrict__ A2s, float* __restrict__ A2d,
    int nbDeg, int nbK1, int nbWt) {
  int bid = blockIdx.x;
  int t = threadIdx.x;
  if (bid < nbDeg) {
    // pass 1 of CSR: count + record within-segment position, 4 edges/thread
    int is64 = *flag;
    int base = bid * 1024;
    int i0 = base + t, i1 = base + 256 + t, i2 = base + 512 + t, i3 = base + 768 + t;
    int d0 = (i0 < E) ? load_idx(ei, E + i0, is64) : -1;
    int d1 = (i1 < E) ? load_idx(ei, E + i1, is64) : -1;
    int d2 = (i2 < E) ? load_idx(ei, E + i2, is64) : -1;
    int d3 = (i3 < E) ? load_idx(ei, E + i3, is64) : -1;
    int p0 = (d0 >= 0) ? atomicAdd(&cnt[d0], 1) : 0;
    int p1 = (d1 >= 0) ? atomicAdd(&cnt[d1], 1) : 0;
    int p2 = (d2 >= 0) ? atomicAdd(&cnt[d2], 1) : 0;
    int p3 = (d3 >= 0) ? atomicAdd(&cnt[d3], 1) : 0;
    if (d0 >= 0) pos[i0] = p0;
    if (d1 >= 0) pos[i1] = p1;
    if (d2 >= 0) pos[i2] = p2;
    if (d3 >= 0) pos[i3] = p3;
  } else if (bid < nbDeg + nbK1) {
    // k1: xa = {x, as1-dot}, adv = ad1-dot, via block-local A1 (3x4 in LDS)
    __shared__ float A1[24];
    if (t < 24) {
      int e = t % 12;
      int k = e >> 2, h = e & 3;
      const float* av = (t < 12) ? as1 : ad1;
      const float* wr = W1 + k * 256 + h * 64;
      const float* a = av + h * 64;
      float v = 0.f;
      for (int c = 0; c < 64; ++c) v += wr[c] * a[c];
      A1[t] = v;
    }
    __syncthreads();
    int n = (bid - nbDeg) * 256 + t;
    if (n < N) {
      float x0 = x[n * 3 + 0], x1 = x[n * 3 + 1], x2 = x[n * 3 + 2];
      f32x4 xv, s, d;
      xv[0] = x0; xv[1] = x1; xv[2] = x2; xv[3] = 0.f;
#pragma unroll
      for (int h = 0; h < 4; ++h) {
        s[h] = x0 * A1[h] + x1 * A1[4 + h] + x2 * A1[8 + h];
        d[h] = x0 * A1[12 + h] + x1 * A1[16 + h] + x2 * A1[20 + h];
      }
      *(f32x4*)(xa + (size_t)n * 8) = xv;
      *(f32x4*)(xa + (size_t)n * 8 + 4) = s;
      *(f32x4*)(adv + (size_t)n * 4) = d;
    }
  } else if (bid < nbDeg + nbK1 + nbWt) {
    // weight transpose + bf16 cast
    int idx = (bid - nbDeg - nbK1) * 256 + t;
    if (idx < 256 * 256) {
      int k = idx >> 8, n = idx & 255;
      w2t[(size_t)n * 256 + k] = f2bf(W2[idx]);
    } else {
      int j = idx - 256 * 256;
      if (j < 256 * 32) {
        int k = j >> 5, n = j & 31;
        w3t[(size_t)n * 256 + k] = f2bf(W3[j]);
      }
    }
  } else {
    // A2s/A2d = W2 a2 (256x4 each)
    int c = t;
#pragma unroll
    for (int h = 0; h < 4; ++h) {
      float vs = 0.f, vd = 0.f;
      const float* wrow = W2 + (size_t)c * 256 + h * 64;
      const float* s2 = as2 + h * 64;
      const float* d2 = ad2 + h * 64;
      for (int cc = 0; cc < 64; ++cc) {
        float w = wrow[cc];
        vs += w * s2[cc];
        vd += w * d2[cc];
      }
      A2s[c * 4 + h] = vs;
      A2d[c * 4 + h] = vd;
    }
  }
}

__global__ __launch_bounds__(256) void scan_phaseA(const int* __restrict__ deg,
                                                   int* __restrict__ bsum, int N) {
  int t = threadIdx.x;
  int base = blockIdx.x * SCAN_CHUNK + t * 8;
  int s = 0;
#pragma unroll
  for (int i = 0; i < 8; ++i) {
    int idx = base + i;
    if (idx < N) s += deg[idx] + 1;
  }
  __shared__ int red[256];
  red[t] = s;
  __syncthreads();
  for (int d = 128; d > 0; d >>= 1) {
    if (t < d) red[t] += red[t + d];
    __syncthreads();
  }
  if (t == 0) bsum[blockIdx.x] = red[0];
}

__global__ __launch_bounds__(256) void scan_phaseC(const int* __restrict__ deg,
                                                   const int* __restrict__ bsum,
                                                   int* __restrict__ rowptr, int N) {
  int t = threadIdx.x;
  __shared__ int blkoff;
  if (t == 0) {
    int o = 0;
    for (int i = 0; i < (int)blockIdx.x; ++i) o += bsum[i];
    blkoff = o;
  }
  int base = blockIdx.x * SCAN_CHUNK + t * 8;
  int v[8];
  int s = 0;
#pragma unroll
  for (int i = 0; i < 8; ++i) {
    int idx = base + i;
    v[i] = (idx < N) ? deg[idx] + 1 : 0;
    s += v[i];
  }
  __shared__ int sh[256];
  sh[t] = s;
  __syncthreads();
  for (int d = 1; d < 256; d <<= 1) {
    int u = (t >= d) ? sh[t - d] : 0;
    __syncthreads();
    sh[t] += u;
    __syncthreads();
  }
  int run = blkoff + sh[t] - s;
#pragma unroll
  for (int i = 0; i < 8; ++i) {
    int idx = base + i;
    if (idx < N) rowptr[idx] = run;
    run += v[i];
  }
  if (base < N && base + 8 >= N) rowptr[N] = run;
}

// pass 2 of CSR: pure permutation write, no atomics, 4 edges/thread
__global__ __launch_bounds__(256) void scatter2_kernel(
    const int* __restrict__ ei, int E, int N, const int* __restrict__ flag,
    const int* __restrict__ rowptr, const int* __restrict__ pos,
    int* __restrict__ colA) {
  int is64 = *flag;
  int ET = E + N;
  int base = blockIdx.x * 1024;
#pragma unroll
  for (int k = 0; k < 4; ++k) {
    int i = base + k * 256 + (int)threadIdx.x;
    if (i < E) {
      int s = load_idx(ei, i, is64);
      int d = load_idx(ei, E + i, is64);
      __builtin_nontemporal_store(s, &colA[rowptr[d] + pos[i]]);
    } else if (i < ET) {
      int n = i - E;
      __builtin_nontemporal_store(n, &colA[rowptr[n + 1] - 1]);  // self loop: last slot
    }
  }
}

// --- k2_fused: layer-1 agg (ONE random 32B line per edge via xa) -----------
__global__ __launch_bounds__(256) void k2_fused(
    const float* __restrict__ xa, const float* __restrict__ adv,
    const int* __restrict__ rowptr, const int* __restrict__ colA,
    const float* __restrict__ W1, const float* __restrict__ b1,
    const float* __restrict__ A2s, const float* __restrict__ A2d,
    unsigned short* __restrict__ h, float* __restrict__ asv2,
    float* __restrict__ adv2, int N) {
  int wv = threadIdx.x >> 6;
  int d = blockIdx.x * 4 + wv;
  if (d >= N) return;
  int lane = threadIdx.x & 63;
  int h4 = lane >> 4, el = lane & 15;
  int r0 = rowptr[d], r1 = rowptr[d + 1];
  int len = r1 - r0;
  float ad = adv[(size_t)d * 4 + h4];
  float m = -1e30f, s = 0.f;
  float ax = 0.f, ay = 0.f, az = 0.f;
  for (int base = 0; base < len; base += 16) {
    int rem = len - base; if (rem > 16) rem = 16;
    float alpha = -1e30f;
    float xv0 = 0.f, xv1 = 0.f, xv2 = 0.f;
    if (el < rem) {
      int sc = colA[r0 + base + el];
      f32x4 xv = *(const f32x4*)(xa + (size_t)sc * 8);
      float av = xa[(size_t)sc * 8 + 4 + h4];
      xv0 = xv[0]; xv1 = xv[1]; xv2 = xv[2];
      float a = av + ad;
      alpha = (a > 0.f) ? a : NEG_SLOPE * a;
    }
    float mx = alpha;
#pragma unroll
    for (int off = 1; off < 16; off <<= 1) mx = fmaxf(mx, __shfl_xor(mx, off));
    float mn = fmaxf(m, mx);
    float scale = __expf(m - mn);
    float w = (el < rem) ? __expf(alpha - mn) : 0.f;
    float cs = w;
#pragma unroll
    for (int off = 1; off < 16; off <<= 1) cs += __shfl_xor(cs, off);
    s = s * scale + cs;
    m = mn;
    ax = ax * scale + w * xv0;
    ay = ay * scale + w * xv1;
    az = az * scale + w * xv2;
  }
  // butterfly: all 16 lanes of the group get the full sums
#pragma unroll
  for (int off = 1; off < 16; off <<= 1) {
    ax += __shfl_xor(ax, off);
    ay += __shfl_xor(ay, off);
    az += __shfl_xor(az, off);
  }
  float inv = 1.f / (s + SM_EPS);
  ax *= inv; ay *= inv; az *= inv;
  // expansion: lane owns channels [lane*4, lane*4+4), head lane>>4 == h4
  float vs[4] = {}, vd[4] = {};
  unsigned short o[4];
#pragma unroll
  for (int j = 0; j < 4; ++j) {
    int c = lane * 4 + j;
    float val = ax * W1[c] + ay * W1[256 + c] + az * W1[512 + c] + b1[c];
    val = fmaxf(val, 0.f);
    o[j] = f2bf(val);
#pragma unroll
    for (int h2 = 0; h2 < 4; ++h2) {
      vs[h2] += val * A2s[c * 4 + h2];
      vd[h2] += val * A2d[c * 4 + h2];
    }
  }
  *(uint2*)(h + (size_t)d * 256 + lane * 4) = *(uint2*)o;
#pragma unroll
  for (int off = 1; off < 64; off <<= 1) {
#pragma unroll
    for (int h2 = 0; h2 < 4; ++h2) {
      vs[h2] += __shfl_xor(vs[h2], off);
      vd[h2] += __shfl_xor(vd[h2], off);
    }
  }
  if (lane == 0) {
    f32x4 sv, dv;
#pragma unroll
    for (int h2 = 0; h2 < 4; ++h2) { sv[h2] = vs[h2]; dv[h2] = vd[h2]; }
    *(f32x4*)(asv2 + (size_t)d * 4) = sv;
    *(f32x4*)(adv2 + (size_t)d * 4) = dv;
  }
}

// --- layer-2 GEMM: [M,256]@[256,256], BM=128 x BN=256, 512 threads ---------
__global__ __launch_bounds__(512) void gemm_mfma_w256(
    const unsigned short* __restrict__ A, const unsigned short* __restrict__ Bt,
    unsigned short* __restrict__ C, int M, int K) {
  constexpr int BM = 128, BK = 64;
  __shared__ unsigned short As[BM][BK + 8];
  __shared__ unsigned short Bs[256][BK + 8];
  const int bm = blockIdx.x * BM;
  const int tid = threadIdx.x, wid = tid >> 6, lane = tid & 63;
  const int wr = wid >> 2, wc = wid & 3;
  const int lrow = lane & 15, lkh = lane >> 4;
  const int srow = tid >> 3, scol = (tid & 7) * 8;
  f32x4 acc[4][4] = {};
  for (int k0 = 0; k0 < K; k0 += BK) {
#pragma unroll
    for (int r0 = 0; r0 < BM; r0 += 64) {
      int r = r0 + srow, gr = bm + r;
      uint4 v = make_uint4(0u, 0u, 0u, 0u);
      if (gr < M) v = *(const uint4*)(A + (size_t)gr * K + k0 + scol);
      *(uint4*)(&As[r][scol]) = v;
    }
#pragma unroll
    for (int r0 = 0; r0 < 256; r0 += 64) {
      int r = r0 + srow;
      uint4 v = *(const uint4*)(Bt + (size_t)r * K + k0 + scol);
      *(uint4*)(&Bs[r][scol]) = v;
    }
    __syncthreads();
#pragma unroll
    for (int kk = 0; kk < 2; ++kk) {
      bf16x8 a[4], b[4];
#pragma unroll
      for (int m = 0; m < 4; ++m)
        a[m] = *(const bf16x8*)(&As[wr * 64 + m * 16 + lrow][kk * 32 + lkh * 8]);
#pragma unroll
      for (int n = 0; n < 4; ++n)
        b[n] = *(const bf16x8*)(&Bs[wc * 64 + n * 16 + lrow][kk * 32 + lkh * 8]);
#pragma unroll
      for (int m = 0; m < 4; ++m)
#pragma unroll
        for (int n = 0; n < 4; ++n)
          acc[m][n] = __builtin_amdgcn_mfma_f32_16x16x32_bf16(a[m], b[n], acc[m][n], 0, 0, 0);
    }
    __syncthreads();
  }
#pragma unroll
  for (int m = 0; m < 4; ++m) {
#pragma unroll
    for (int q = 0; q < 4; ++q) {
      int grow = bm + wr * 64 + m * 16 + lkh * 4 + q;
      if (grow < M) {
#pragma unroll
        for (int n = 0; n < 4; ++n)
          C[(size_t)grow * 256 + wc * 64 + n * 16 + lrow] = f2bf(acc[m][n][q]);
      }
    }
  }
}

// --- layer-3 GEMM: BM=128 x BN=32 (full width), fused attn (H=1) -----------
template <int WR, int WC, int ATT_H>
__global__ __launch_bounds__(64 * WR * WC) void gemm_mfma(
    const unsigned short* __restrict__ A, const unsigned short* __restrict__ Bt,
    unsigned short* __restrict__ C, const float* __restrict__ a_src,
    const float* __restrict__ a_dst, float* __restrict__ asv, float* __restrict__ adv,
    int M, int N, int K) {
  constexpr int BM = 32 * WR, BN = 32 * WC, BK = 64;
  constexpr int T = 64 * WR * WC;
  constexpr int RPP = T / 8;
  __shared__ unsigned short As[BM][BK + 8];
  __shared__ unsigned short Bs[BN][BK + 8];
  const int bm = blockIdx.y * BM, bn = blockIdx.x * BN;
  const int tid = threadIdx.x, wid = tid >> 6, lane = tid & 63;
  const int wr = wid / WC, wc = wid % WC;
  const int lrow = lane & 15, lkh = lane >> 4;
  const int srow = tid >> 3, scol = (tid & 7) * 8;
  f32x4 acc[2][2] = {};
  for (int k0 = 0; k0 < K; k0 += BK) {
#pragma unroll
    for (int r0 = 0; r0 < BM; r0 += RPP) {
      int r = r0 + srow, gr = bm + r;
      uint4 v = make_uint4(0u, 0u, 0u, 0u);
      if (gr < M) v = *(const uint4*)(A + (size_t)gr * K + k0 + scol);
      *(uint4*)(&As[r][scol]) = v;
    }
#pragma unroll
    for (int r0 = 0; r0 < BN; r0 += RPP) {
      int r = r0 + srow;
      if (r < BN) {
        int gn = bn + r;
        uint4 v = *(const uint4*)(Bt + (size_t)gn * K + k0 + scol);
        *(uint4*)(&Bs[r][scol]) = v;
      }
    }
    __syncthreads();
#pragma unroll
    for (int kk = 0; kk < 2; ++kk) {
      bf16x8 a0 = *(const bf16x8*)(&As[wr * 32 + lrow][kk * 32 + lkh * 8]);
      bf16x8 a1 = *(const bf16x8*)(&As[wr * 32 + 16 + lrow][kk * 32 + lkh * 8]);
      bf16x8 b0 = *(const bf16x8*)(&Bs[wc * 32 + lrow][kk * 32 + lkh * 8]);
      bf16x8 b1 = *(const bf16x8*)(&Bs[wc * 32 + 16 + lrow][kk * 32 + lkh * 8]);
      acc[0][0] = __builtin_amdgcn_mfma_f32_16x16x32_bf16(a0, b0, acc[0][0], 0, 0, 0);
      acc[0][1] = __builtin_amdgcn_mfma_f32_16x16x32_bf16(a0, b1, acc[0][1], 0, 0, 0);
      acc[1][0] = __builtin_amdgcn_mfma_f32_16x16x32_bf16(a1, b0, acc[1][0], 0, 0, 0);
      acc[1][1] = __builtin_amdgcn_mfma_f32_16x16x32_bf16(a1, b1, acc[1][1], 0, 0, 0);
    }
    __syncthreads();
  }
#pragma unroll
  for (int m = 0; m < 2; ++m) {
#pragma unroll
    for (int q = 0; q < 4; ++q) {
      int grow = bm + wr * 32 + m * 16 + lkh * 4 + q;
      if (grow < M) {
#pragma unroll
        for (int n = 0; n < 2; ++n) {
          int gcol = bn + wc * 32 + n * 16 + lrow;
          C[(size_t)grow * N + gcol] = f2bf(acc[m][n][q]);
        }
      }
    }
  }
  const int hh = (ATT_H == 1) ? 0 : (int)blockIdx.x;
  float asl[2], adl[2];
#pragma unroll
  for (int n = 0; n < 2; ++n) {
    int c = wc * 32 + n * 16 + lrow;
    asl[n] = a_src[hh * BN + c];
    adl[n] = a_dst[hh * BN + c];
  }
#pragma unroll
  for (int m = 0; m < 2; ++m) {
#pragma unroll
    for (int q = 0; q < 4; ++q) {
      float ps = acc[m][0][q] * asl[0] + acc[m][1][q] * asl[1];
      float pd = acc[m][0][q] * adl[0] + acc[m][1][q] * adl[1];
#pragma unroll
      for (int off = 1; off < 16; off <<= 1) {
        ps += __shfl_xor(ps, off);
        pd += __shfl_xor(pd, off);
      }
      int grow = bm + wr * 32 + m * 16 + lkh * 4 + q;
      if (lrow == 0 && grow < M) {
        asv[(size_t)grow * ATT_H + hh] = ps;
        adv[(size_t)grow * ATT_H + hh] = pd;
      }
    }
  }
}

// --- single-pass fused softmax+gather, H=4 C=64: wave per dst --------------
template <bool RELU>
__global__ __launch_bounds__(256) void gat_fused256(
    const unsigned short* __restrict__ hbuf, const float* __restrict__ asv,
    const float* __restrict__ adv, const int* __restrict__ rowptr,
    const int* __restrict__ colA, const float* __restrict__ bias,
    unsigned short* __restrict__ outb, int N) {
  int wv = threadIdx.x >> 6;
  int d = blockIdx.x * 4 + wv;
  if (d >= N) return;
  int lane = threadIdx.x & 63;
  int h4 = lane >> 4, el = lane & 15;       // stats role
  int g = lane >> 5, c32 = lane & 31;       // gather role
  int hh = c32 >> 3;
  int r0 = rowptr[d], r1 = rowptr[d + 1];
  int len = r1 - r0;
  float ad = adv[(size_t)d * 4 + h4];
  float m = -1e30f, s = 0.f;
  float acc[8] = {};
  const int hsrc = hh * 16;
  for (int base = 0; base < len; base += 16) {
    int rem = len - base; if (rem > 16) rem = 16;
    int sc = 0;
    float alpha = -1e30f;
    if (el < rem) {
      sc = colA[r0 + base + el];
      float a = asv[(size_t)sc * 4 + h4] + ad;
      alpha = (a > 0.f) ? a : NEG_SLOPE * a;
    }
    float mx = alpha;
#pragma unroll
    for (int off = 1; off < 16; off <<= 1) mx = fmaxf(mx, __shfl_xor(mx, off));
    float mn = fmaxf(m, mx);
    float scale = __expf(m - mn);
    float w = (el < rem) ? __expf(alpha - mn) : 0.f;
    float cs = w;
#pragma unroll
    for (int off = 1; off < 16; off <<= 1) cs += __shfl_xor(cs, off);
    s = s * scale + cs;
    m = mn;
    float scale_h = __shfl(scale, hsrc);
#pragma unroll
    for (int j = 0; j < 8; ++j) acc[j] *= scale_h;
    int e2 = 0;
    for (; e2 + 4 <= rem; e2 += 4) {
      int ea = e2 + g, eb = e2 + 2 + g;
      float wa = __shfl(w, hsrc + ea);
      int sa = __shfl(sc, hsrc + ea);
      float wb = __shfl(w, hsrc + eb);
      int sb = __shfl(sc, hsrc + eb);
      uint4 hva = *(const uint4*)(hbuf + (size_t)sa * 256 + c32 * 8);
      uint4 hvb = *(const uint4*)(hbuf + (size_t)sb * 256 + c32 * 8);
      float f0, f1;
      bf2x(hva.x, f0, f1); acc[0] += wa * f0; acc[1] += wa * f1;
      bf2x(hva.y, f0, f1); acc[2] += wa * f0; acc[3] += wa * f1;
      bf2x(hva.z, f0, f1); acc[4] += wa * f0; acc[5] += wa * f1;
      bf2x(hva.w, f0, f1); acc[6] += wa * f0; acc[7] += wa * f1;
      bf2x(hvb.x, f0, f1); acc[0] += wb * f0; acc[1] += wb * f1;
      bf2x(hvb.y, f0, f1); acc[2] += wb * f0; acc[3] += wb * f1;
      bf2x(hvb.z, f0, f1); acc[4] += wb * f0; acc[5] += wb * f1;
      bf2x(hvb.w, f0, f1); acc[6] += wb * f0; acc[7] += wb * f1;
    }
    for (; e2 < rem; e2 += 2) {
      int e = e2 + g;
      float w_e = __shfl(w, hsrc + (e & 15));
      int sc_e = __shfl(sc, hsrc + (e & 15));
      uint4 hv = *(const uint4*)(hbuf + (size_t)sc_e * 256 + c32 * 8);
      float f0, f1;
      bf2x(hv.x, f0, f1); acc[0] += w_e * f0; acc[1] += w_e * f1;
      bf2x(hv.y, f0, f1); acc[2] += w_e * f0; acc[3] += w_e * f1;
      bf2x(hv.z, f0, f1); acc[4] += w_e * f0; acc[5] += w_e * f1;
      bf2x(hv.w, f0, f1); acc[6] += w_e * f0; acc[7] += w_e * f1;
    }
  }
#pragma unroll
  for (int j = 0; j < 8; ++j) acc[j] += __shfl_xor(acc[j], 32);
  float inv = 1.f / (__shfl(s, hsrc) + SM_EPS);
  if (g == 0) {
    unsigned short o[8];
#pragma unroll
    for (int j = 0; j < 8; ++j) {
      float v = acc[j] * inv + bias[c32 * 8 + j];
      if (RELU) v = fmaxf(v, 0.f);
      o[j] = f2bf(v);
    }
    __builtin_nontemporal_store(*(u32x4*)o, (u32x4*)(outb + (size_t)d * 256 + c32 * 8));
  }
}

// --- single-pass fused softmax+gather, H=1 C=32 (layer 3), fp32 out --------
__global__ __launch_bounds__(256) void gat_fused32(
    const unsigned short* __restrict__ hbuf, const float* __restrict__ asv,
    const float* __restrict__ adv, const int* __restrict__ rowptr,
    const int* __restrict__ colA, const float* __restrict__ bias,
    float* __restrict__ out, int N) {
  int wv = threadIdx.x >> 6;
  int d = blockIdx.x * 4 + wv;
  if (d >= N) return;
  int lane = threadIdx.x & 63;
  int slot = lane >> 3, ci = lane & 7;
  int r0 = rowptr[d], r1 = rowptr[d + 1];
  int len = r1 - r0;
  float ad = adv[d];
  float m = -1e30f, s = 0.f;
  float a0 = 0.f, a1 = 0.f, a2 = 0.f, a3 = 0.f;
  for (int base = 0; base < len; base += 64) {
    int rem = len - base; if (rem > 64) rem = 64;
    int sc = 0;
    float alpha = -1e30f;
    if (lane < rem) {
      sc = colA[r0 + base + lane];
      float a = asv[sc] + ad;
      alpha = (a > 0.f) ? a : NEG_SLOPE * a;
    }
    float mx = alpha;
#pragma unroll
    for (int off = 1; off < 64; off <<= 1) mx = fmaxf(mx, __shfl_xor(mx, off));
    float mn = fmaxf(m, mx);
    float scale = __expf(m - mn);
    float w = (lane < rem) ? __expf(alpha - mn) : 0.f;
    float cs = w;
#pragma unroll
    for (int off = 1; off < 64; off <<= 1) cs += __shfl_xor(cs, off);
    s = s * scale + cs;
    m = mn;
    a0 *= scale; a1 *= scale; a2 *= scale; a3 *= scale;
    for (int e2 = 0; e2 < rem; e2 += 8) {
      int e = e2 + slot;
      float w_e = __shfl(w, e);
      int sc_e = __shfl(sc, e);
      uint2 hv = *(const uint2*)(hbuf + (size_t)sc_e * 32 + ci * 4);
      float f0, f1;
      bf2x(hv.x, f0, f1); a0 += w_e * f0; a1 += w_e * f1;
      bf2x(hv.y, f0, f1); a2 += w_e * f0; a3 += w_e * f1;
    }
  }
#pragma unroll
  for (int off = 8; off < 64; off <<= 1) {
    a0 += __shfl_xor(a0, off);
    a1 += __shfl_xor(a1, off);
    a2 += __shfl_xor(a2, off);
    a3 += __shfl_xor(a3, off);
  }
  if (slot == 0) {
    float inv = 1.f / (s + SM_EPS);
    f32x4 o;
    o.x = a0 * inv + bias[ci * 4 + 0];
    o.y = a1 * inv + bias[ci * 4 + 1];
    o.z = a2 * inv + bias[ci * 4 + 2];
    o.w = a3 * inv + bias[ci * 4 + 3];
    __builtin_nontemporal_store(o, (f32x4*)(out + (size_t)d * 32 + ci * 4));
  }
}

// ---------------------------------------------------------------------------
extern "C" void kernel_launch(void* const* d_in, const int* in_sizes, int n_in,
                              void* d_out, int out_size, void* d_ws, size_t ws_size,
                              hipStream_t stream) {
  const float* x   = (const float*)d_in[0];
  const int*   ei  = (const int*)d_in[1];
  const float* W1  = (const float*)d_in[2];
  const float* as1 = (const float*)d_in[3];
  const float* ad1 = (const float*)d_in[4];
  const float* b1  = (const float*)d_in[5];
  const float* W2  = (const float*)d_in[6];
  const float* as2 = (const float*)d_in[7];
  const float* ad2 = (const float*)d_in[8];
  const float* b2  = (const float*)d_in[9];
  const float* W3  = (const float*)d_in[10];
  const float* as3 = (const float*)d_in[11];
  const float* ad3 = (const float*)d_in[12];
  const float* b3  = (const float*)d_in[13];
  float* out = (float*)d_out;

  const int N = in_sizes[0] / 3;
  const int E = in_sizes[1] / 2;
  const int ET = E + N;  // with self loops

  char* ws = (char*)d_ws;
  size_t off = 0;
  auto alloc = [&](size_t bytes) -> void* {
    void* p = ws + off;
    off = (off + bytes + 255) & ~(size_t)255;
    return p;
  };
  unsigned short* bufA = (unsigned short*)alloc((size_t)N * 256 * 2);
  unsigned short* bufB = (unsigned short*)alloc((size_t)N * 256 * 2);
  unsigned short* w2t  = (unsigned short*)alloc((size_t)256 * 256 * 2);
  unsigned short* w3t  = (unsigned short*)alloc((size_t)32 * 256 * 2);
  float* xa     = (float*)alloc((size_t)N * 8 * 4);
  float* adbuf  = (float*)alloc((size_t)N * 4 * 4);
  float* asbuf2 = (float*)alloc((size_t)N * 4 * 4);
  float* adbuf2 = (float*)alloc((size_t)N * 4 * 4);
  float* asbuf3 = (float*)alloc((size_t)N * 4 * 4);
  float* adbuf3 = (float*)alloc((size_t)N * 4 * 4);
  int*   rowptr = (int*)alloc((size_t)(N + 1) * 4);
  int*   cnt    = (int*)alloc((size_t)N * 4);
  int*   posb   = (int*)alloc((size_t)E * 4);
  int*   colA   = (int*)alloc((size_t)ET * 4);
  int*   bsum   = (int*)alloc(1024);
  int*   dflag  = (int*)alloc(256);
  float* A2s    = (float*)alloc(1024 * 4);
  float* A2d    = (float*)alloc(1024 * 4);
  (void)ws_size;

  const int nScanB = (N + SCAN_CHUNK - 1) / SCAN_CHUNK;
  const int nbDeg = (E + 1023) / 1024;
  const int nbK1  = (N + 255) / 256;
  const int nbWt  = (256 * 256 + 256 * 32 + 255) / 256;

  // --- CSR build + weight prep (fused) ---
  zero_detect<<<(N + 255) / 256, 256, 0, stream>>>(ei, dflag, cnt, N);
  prep_mega<<<nbDeg + nbK1 + nbWt + 1, 256, 0, stream>>>(
      ei, E, dflag, cnt, posb, x, W1, as1, ad1, xa, adbuf, N,
      W2, W3, w2t, w3t, as2, ad2, A2s, A2d, nbDeg, nbK1, nbWt);
  scan_phaseA<<<nScanB, 256, 0, stream>>>(cnt, bsum, N);
  scan_phaseC<<<nScanB, 256, 0, stream>>>(cnt, bsum, rowptr, N);
  scatter2_kernel<<<(ET + 1023) / 1024, 256, 0, stream>>>(ei, E, N, dflag, rowptr, posb, colA);

  const int nb4 = (N + 3) / 4;

  // --- layer 1: fused agg(xa) + W1 expand + asv2 epilogue -> bufB ---
  k2_fused<<<nb4, 256, 0, stream>>>(xa, adbuf, rowptr, colA, W1, b1,
                                    A2s, A2d, bufB, asbuf2, adbuf2, N);

  // --- layer 2: h2 = h1 @ W2 (MFMA) -> bufA ; fused agg -> bufB ---
  gemm_mfma_w256<<<(N + 127) / 128, 512, 0, stream>>>(bufB, w2t, bufA, N, 256);
  gat_fused256<true><<<nb4, 256, 0, stream>>>(bufA, asbuf2, adbuf2, rowptr, colA, b2, bufB, N);

  // --- layer 3: MFMA GEMM+attn -> bufA[0:N*32] ; fused agg -> out ---
  {
    dim3 grid(1, (N + 127) / 128);
    gemm_mfma<4, 1, 1><<<grid, 256, 0, stream>>>(bufB, w3t, bufA, as3, ad3, asbuf3, adbuf3,
                                                 N, 32, 256);
  }
  gat_fused32<<<nb4, 256, 0, stream>>>(bufA, asbuf3, adbuf3, rowptr, colA, b3, out, N);
}